// Round 1
// 365.362 us; speedup vs baseline: 1.0046x; 1.0046x over previous
//
#include <hip/hip_runtime.h>

// RegressionWisard predict (centrality='mean')
//   input:  [B=4096, E=8192] int32 bits
//   map:    [E] permutation int32 (identity in the benchmark)
//   counts: [N=512, 65536] int32
//   sums:   [N=512, 65536] float32
//   out:    [B] float32 = nan_to_num(sum(s where c>0) / sum(c where c>0))
//
// R3: traffic is at floor (316 MB vs ~297 MB ideal); BW is 28% of peak ->
// latency/MLP-bound. Remove the ballot/LDS staging + both barriers: with an
// identity (contiguous-per-neuron) mapping, each thread's 16 input bits are
// one 64B line -> 4x nontemporal dwordx4 per (sample, neuron). Per-thread
// independent loads go 8 -> 24 with no dead address-compute window.
// General-mapping fallback (scalar bit gathers) kept for correctness.

constexpr int BATCH   = 4096;
constexpr int ENTRY   = 8192;
constexpr int TUP     = 16;
constexpr int NEUR    = ENTRY / TUP;    // 512
constexpr int THREADS = 256;
constexpr int SPB     = 2;              // samples per block
constexpr int KPT     = NEUR / THREADS; // 2 neurons per thread

typedef int v4i __attribute__((ext_vector_type(4)));

__global__ __launch_bounds__(THREADS) void wisard_kernel(
    const int*   __restrict__ input,
    const int*   __restrict__ mapping,
    const int*   __restrict__ counts,
    const float* __restrict__ sums,
    float*       __restrict__ out)
{
    __shared__ float s_resp[SPB][THREADS / 64];
    __shared__ int   s_cnt [SPB][THREADS / 64];

    const int tid  = threadIdx.x;
    const int lane = tid & 63;
    const int wv   = tid >> 6;
    const int b0   = blockIdx.x * SPB;

    int   cv[SPB][KPT];
    float sv[SPB][KPT];

    #pragma unroll
    for (int k = 0; k < KPT; ++k) {
        const int n = tid + k * THREADS;
        const int* map_n = mapping + n * TUP;

        // Contiguity check: neuron n's 16 bits are map_n[0]..map_n[0]+15
        // and 16B-aligned -> fast vector path (true for identity mapping).
        const int m0 = map_n[0];
        bool contig = ((m0 & 3) == 0);
        #pragma unroll
        for (int t = 1; t < TUP; ++t) contig &= (map_n[t] == m0 + t);

        int addr[SPB];
        if (contig) {
            #pragma unroll
            for (int s = 0; s < SPB; ++s) {
                const v4i* p = reinterpret_cast<const v4i*>(
                    input + (size_t)(b0 + s) * ENTRY + m0);
                const v4i w0 = __builtin_nontemporal_load(p);
                const v4i w1 = __builtin_nontemporal_load(p + 1);
                const v4i w2 = __builtin_nontemporal_load(p + 2);
                const v4i w3 = __builtin_nontemporal_load(p + 3);
                // bit 0 of the tuple is the MSB of the address
                addr[s] = ((w0.x & 1) << 15) | ((w0.y & 1) << 14)
                        | ((w0.z & 1) << 13) | ((w0.w & 1) << 12)
                        | ((w1.x & 1) << 11) | ((w1.y & 1) << 10)
                        | ((w1.z & 1) <<  9) | ((w1.w & 1) <<  8)
                        | ((w2.x & 1) <<  7) | ((w2.y & 1) <<  6)
                        | ((w2.z & 1) <<  5) | ((w2.w & 1) <<  4)
                        | ((w3.x & 1) <<  3) | ((w3.y & 1) <<  2)
                        | ((w3.z & 1) <<  1) |  (w3.w & 1);
            }
        } else {
            // general permutation: scalar bit gathers (cold path)
            #pragma unroll
            for (int s = 0; s < SPB; ++s) {
                const int* row = input + (size_t)(b0 + s) * ENTRY;
                int a = 0;
                #pragma unroll
                for (int t = 0; t < TUP; ++t) a = (a << 1) | (row[map_n[t]] & 1);
                addr[s] = a;
            }
        }

        // Issue both table gathers per sample; results consumed only at the
        // end, so k=0's loads stay in flight across k=1's input loads.
        #pragma unroll
        for (int s = 0; s < SPB; ++s) {
            const size_t idx = ((size_t)n << 16) | (unsigned)addr[s];
            cv[s][k] = counts[idx];
            sv[s][k] = sums  [idx];
        }
    }

    float resp[SPB];
    int   cnt [SPB];
    #pragma unroll
    for (int s = 0; s < SPB; ++s) {
        resp[s] = 0.0f; cnt[s] = 0;
        #pragma unroll
        for (int k = 0; k < KPT; ++k) {
            const bool tr = cv[s][k] > 0;
            resp[s] += tr ? sv[s][k] : 0.0f;
            cnt [s] += tr ? cv[s][k] : 0;
        }
    }

    // Block reduction per sample
    #pragma unroll
    for (int s = 0; s < SPB; ++s) {
        float r = resp[s]; int c = cnt[s];
        #pragma unroll
        for (int off = 32; off > 0; off >>= 1) {
            r += __shfl_down(r, off, 64);
            c += __shfl_down(c, off, 64);
        }
        if (lane == 0) { s_resp[s][wv] = r; s_cnt[s][wv] = c; }
    }
    __syncthreads();
    if (tid < SPB) {
        float r = 0.0f; int c = 0;
        #pragma unroll
        for (int w = 0; w < THREADS / 64; ++w) { r += s_resp[tid][w]; c += s_cnt[tid][w]; }
        out[b0 + tid] = (c > 0) ? (r / (float)c) : 0.0f;   // nan_to_num(0/0)==0
    }
}

extern "C" void kernel_launch(void* const* d_in, const int* in_sizes, int n_in,
                              void* d_out, int out_size, void* d_ws, size_t ws_size,
                              hipStream_t stream) {
    (void)in_sizes; (void)n_in; (void)out_size; (void)d_ws; (void)ws_size;
    const int*   input   = (const int*)d_in[0];
    const int*   mapping = (const int*)d_in[1];
    const int*   counts  = (const int*)d_in[2];
    const float* sums    = (const float*)d_in[3];
    float*       out     = (float*)d_out;

    wisard_kernel<<<BATCH / SPB, THREADS, 0, stream>>>(input, mapping, counts, sums, out);
}